// Round 1
// baseline (368.770 us; speedup 1.0000x reference)
//
#include <hip/hip_runtime.h>
#include <hip/hip_bf16.h>

typedef __attribute__((ext_vector_type(8))) short short8;
typedef __attribute__((ext_vector_type(4))) float f32x4;

#define MFMA16(a, b, c) __builtin_amdgcn_mfma_f32_16x16x32_bf16((a), (b), (c), 0, 0, 0)

// dims
#define NB 2
#define NSEQ 4096
#define DMODEL 512
#define NH 8
#define HD 64
#define CSTRIDE (NB * NSEQ * DMODEL)  // 4194304

static __device__ __forceinline__ unsigned short f2bf(float f) {
    unsigned u = __builtin_bit_cast(unsigned, f);
    u += 0x7fffu + ((u >> 16) & 1u);
    return (unsigned short)(u >> 16);
}

static __device__ __forceinline__ short8 cvt8(float4 a, float4 b) {
    short8 r;
    r[0] = (short)f2bf(a.x); r[1] = (short)f2bf(a.y);
    r[2] = (short)f2bf(a.z); r[3] = (short)f2bf(a.w);
    r[4] = (short)f2bf(b.x); r[5] = (short)f2bf(b.y);
    r[6] = (short)f2bf(b.z); r[7] = (short)f2bf(b.w);
    return r;
}

// ---------------------------------------------------------------------------
// Flash attention: grid (64 q-tiles, 16 b*h), 256 threads (4 waves).
// Each wave: 16 q-rows. KV tiles of 64 keys staged in LDS (bf16, swizzled).
// Writes O (softmax(QK^T*scale)V) as bf16 [B, N, D] into workspace.
// ---------------------------------------------------------------------------
__global__ __launch_bounds__(256, 4)
void attn_kernel(const float* __restrict__ x, unsigned short* __restrict__ Obf) {
    __shared__ __attribute__((aligned(16))) unsigned short K_lds[64 * 64];  // [key][d]
    __shared__ __attribute__((aligned(16))) unsigned short V_lds[64 * 64];  // [d][key] (transposed)
    __shared__ __attribute__((aligned(16))) unsigned short P_lds[4 * 16 * 64];  // per-wave [q][key]

    const int tid = threadIdx.x;
    const int lane = tid & 63;
    const int wv = tid >> 6;
    const int g = lane >> 4;
    const int l4 = lane & 15;

    const int bh = blockIdx.y;
    const int b = bh >> 3, h = bh & 7;
    const int qbase = blockIdx.x * 64;

    const float* xq = x + (size_t)b * NSEQ * DMODEL + h * HD;
    const float* xk = xq + (size_t)CSTRIDE;
    const float* xv = xq + (size_t)2 * CSTRIDE;

    // Hoist Q fragments: A[row=lane%16][k = 32c + 8g + i]
    short8 qf[2];
    {
        const int qrow = qbase + wv * 16 + l4;
        const float* qp = xq + (size_t)qrow * DMODEL + g * 8;
#pragma unroll
        for (int c = 0; c < 2; ++c) {
            float4 a0 = *reinterpret_cast<const float4*>(qp + c * 32);
            float4 a1 = *reinterpret_cast<const float4*>(qp + c * 32 + 4);
            qf[c] = cvt8(a0, a1);
        }
    }

    f32x4 oacc[4];
#pragma unroll
    for (int dt = 0; dt < 4; ++dt) oacc[dt] = (f32x4){0.f, 0.f, 0.f, 0.f};
    float mrow[4], lrow[4];
#pragma unroll
    for (int r = 0; r < 4; ++r) { mrow[r] = -1e30f; lrow[r] = 0.f; }

    const float ls = 0.125f * 1.44269504088896340736f;  // scale * log2(e)

    for (int kt = 0; kt < NSEQ / 64; ++kt) {
        // ---- stage K (row-major) and V (transposed), both swizzled ----
#pragma unroll
        for (int j = 0; j < 2; ++j) {
            const int cid = tid + 256 * j;       // 512 chunks = 64 rows x 8
            const int row = cid >> 3;            // key index within tile
            const int d0 = (cid & 7) * 8;
            const float* kp = xk + (size_t)(kt * 64 + row) * DMODEL + d0;
            float4 a0 = *reinterpret_cast<const float4*>(kp);
            float4 a1 = *reinterpret_cast<const float4*>(kp + 4);
            int koff = (row * 128 + d0 * 2) ^ ((row & 7) << 4);
            *reinterpret_cast<short8*>((char*)K_lds + koff) = cvt8(a0, a1);

            const float* vp = xv + (size_t)(kt * 64 + row) * DMODEL + d0;
            float4 v0 = *reinterpret_cast<const float4*>(vp);
            float4 v1 = *reinterpret_cast<const float4*>(vp + 4);
            float tv[8] = {v0.x, v0.y, v0.z, v0.w, v1.x, v1.y, v1.z, v1.w};
#pragma unroll
            for (int i = 0; i < 8; ++i) {
                int d = d0 + i;
                int voff = (d * 128 + row * 2) ^ ((d & 7) << 4);
                *reinterpret_cast<unsigned short*>((char*)V_lds + voff) = f2bf(tv[i]);
            }
        }
        __syncthreads();

        // ---- S = Q K^T (4 key-subtiles of 16), in log2-scaled units ----
        f32x4 zt[4];
#pragma unroll
        for (int t = 0; t < 4; ++t) {
            f32x4 acc = (f32x4){0.f, 0.f, 0.f, 0.f};
#pragma unroll
            for (int c = 0; c < 2; ++c) {
                const int key = t * 16 + l4;
                int off = (key * 128 + (c * 32 + g * 8) * 2) ^ ((key & 7) << 4);
                short8 kb = *reinterpret_cast<const short8*>((const char*)K_lds + off);
                acc = MFMA16(qf[c], kb, acc);
            }
#pragma unroll
            for (int r = 0; r < 4; ++r) zt[t][r] = acc[r] * ls;
        }

        // ---- online softmax (rows live in (g, reg); reduce over 16 lanes) ----
        float rs[4];
#pragma unroll
        for (int r = 0; r < 4; ++r) {
            float mx = fmaxf(fmaxf(zt[0][r], zt[1][r]), fmaxf(zt[2][r], zt[3][r]));
            mx = fmaxf(mx, __shfl_xor(mx, 1));
            mx = fmaxf(mx, __shfl_xor(mx, 2));
            mx = fmaxf(mx, __shfl_xor(mx, 4));
            mx = fmaxf(mx, __shfl_xor(mx, 8));
            float mn = fmaxf(mrow[r], mx);
            rs[r] = exp2f(mrow[r] - mn);
            mrow[r] = mn;
        }
#pragma unroll
        for (int r = 0; r < 4; ++r) {
            float s = 0.f;
#pragma unroll
            for (int t = 0; t < 4; ++t) {
                float p = exp2f(zt[t][r] - mrow[r]);
                zt[t][r] = p;
                s += p;
            }
            s += __shfl_xor(s, 1);
            s += __shfl_xor(s, 2);
            s += __shfl_xor(s, 4);
            s += __shfl_xor(s, 8);
            lrow[r] = lrow[r] * rs[r] + s;
#pragma unroll
            for (int dt = 0; dt < 4; ++dt) oacc[dt][r] *= rs[r];
        }

        // ---- P -> per-wave LDS (bf16), then read back as A-fragments ----
#pragma unroll
        for (int t = 0; t < 4; ++t) {
#pragma unroll
            for (int r = 0; r < 4; ++r) {
                int q = g * 4 + r, key = t * 16 + l4;
                int off = (wv * 2048 + q * 128 + key * 2) ^ ((q & 7) << 4);
                *reinterpret_cast<unsigned short*>((char*)P_lds + off) = f2bf(zt[t][r]);
            }
        }
#pragma unroll
        for (int c = 0; c < 2; ++c) {
            int poff = (wv * 2048 + l4 * 128 + (c * 32 + g * 8) * 2) ^ ((l4 & 7) << 4);
            short8 pa = *reinterpret_cast<const short8*>((const char*)P_lds + poff);
#pragma unroll
            for (int dt = 0; dt < 4; ++dt) {
                int d = dt * 16 + l4;
                int voff = (d * 128 + (c * 32 + g * 8) * 2) ^ ((d & 7) << 4);
                short8 vb = *reinterpret_cast<const short8*>((const char*)V_lds + voff);
                oacc[dt] = MFMA16(pa, vb, oacc[dt]);
            }
        }
        __syncthreads();
    }

    // ---- epilogue: O = acc / l, write bf16 to workspace [B, N, D] ----
#pragma unroll
    for (int r = 0; r < 4; ++r) {
        float inv = 1.0f / lrow[r];
        int qrow = qbase + wv * 16 + g * 4 + r;
#pragma unroll
        for (int dt = 0; dt < 4; ++dt) {
            int d = dt * 16 + l4;
            Obf[(size_t)(b * NSEQ + qrow) * DMODEL + h * HD + d] =
                f2bf(oacc[dt][r] * inv);
        }
    }
}

// ---------------------------------------------------------------------------
// Projection: Y[8192,512] = O_bf16 @ W^T + bias (W fp32 [512,512], row-major).
// grid (128 m-tiles, 8 n-tiles), 256 threads (4 waves), 64x64 tile.
// ---------------------------------------------------------------------------
__global__ __launch_bounds__(256, 4)
void proj_kernel(const unsigned short* __restrict__ Obf, const float* __restrict__ W,
                 const float* __restrict__ bias, float* __restrict__ out) {
    __shared__ __attribute__((aligned(16))) unsigned short W_lds[64 * 64];  // [j][k]

    const int tid = threadIdx.x;
    const int lane = tid & 63;
    const int wv = tid >> 6;
    const int g = lane >> 4;
    const int l4 = lane & 15;

    const int bm = blockIdx.x;
    const int bn = blockIdx.y;

    f32x4 acc[4];
#pragma unroll
    for (int jt = 0; jt < 4; ++jt) acc[jt] = (f32x4){0.f, 0.f, 0.f, 0.f};

    for (int kc = 0; kc < DMODEL / 64; ++kc) {
        // stage W tile: W_lds[j][k] = W[bn*64+j][kc*64+k]  (B-operand: col=j, k contiguous)
#pragma unroll
        for (int j = 0; j < 2; ++j) {
            int cid = tid + 256 * j;
            int row = cid >> 3;
            int d0 = (cid & 7) * 8;
            const float* wp = W + (size_t)(bn * 64 + row) * DMODEL + kc * 64 + d0;
            float4 a0 = *reinterpret_cast<const float4*>(wp);
            float4 a1 = *reinterpret_cast<const float4*>(wp + 4);
            int off = (row * 128 + d0 * 2) ^ ((row & 7) << 4);
            *reinterpret_cast<short8*>((char*)W_lds + off) = cvt8(a0, a1);
        }
        __syncthreads();

#pragma unroll
        for (int sub = 0; sub < 2; ++sub) {
            const unsigned short* ap =
                Obf + (size_t)(bm * 64 + wv * 16 + l4) * DMODEL + kc * 64 + sub * 32 + g * 8;
            short8 a = *reinterpret_cast<const short8*>(ap);
#pragma unroll
            for (int jt = 0; jt < 4; ++jt) {
                int jj = jt * 16 + l4;
                int off = (jj * 128 + (sub * 32 + g * 8) * 2) ^ ((jj & 7) << 4);
                short8 wb = *reinterpret_cast<const short8*>((const char*)W_lds + off);
                acc[jt] = MFMA16(a, wb, acc[jt]);
            }
        }
        __syncthreads();
    }

#pragma unroll
    for (int jt = 0; jt < 4; ++jt) {
        int jg = bn * 64 + jt * 16 + l4;
        float bj = bias[jg];
#pragma unroll
        for (int r = 0; r < 4; ++r) {
            int ig = bm * 64 + wv * 16 + g * 4 + r;
            out[(size_t)ig * DMODEL + jg] = acc[jt][r] + bj;
        }
    }
}

extern "C" void kernel_launch(void* const* d_in, const int* in_sizes, int n_in,
                              void* d_out, int out_size, void* d_ws, size_t ws_size,
                              hipStream_t stream) {
    const float* x = (const float*)d_in[0];       // [3, 2, 4096, 512] fp32
    const float* W = (const float*)d_in[1];       // [512, 512] fp32
    const float* bias = (const float*)d_in[2];    // [512] fp32
    float* out = (float*)d_out;                   // [2, 4096, 512] fp32
    unsigned short* Obf = (unsigned short*)d_ws;  // bf16 [2, 4096, 512] = 8 MB

    dim3 gA(NSEQ / 64, NB * NH);  // (64, 16)
    attn_kernel<<<gA, 256, 0, stream>>>(x, Obf);

    dim3 gP(NB * NSEQ / 64, DMODEL / 64);  // (128, 8)
    proj_kernel<<<gP, 256, 0, stream>>>(Obf, W, bias, out);
}

// Round 2
// 186.660 us; speedup vs baseline: 1.9756x; 1.9756x over previous
//
#include <hip/hip_runtime.h>
#include <hip/hip_bf16.h>

typedef __attribute__((ext_vector_type(8))) short short8;
typedef __attribute__((ext_vector_type(4))) float f32x4;

#define MFMA16(a, b, c) __builtin_amdgcn_mfma_f32_16x16x32_bf16((a), (b), (c), 0, 0, 0)

// dims
#define NB 2
#define NSEQ 4096
#define DMODEL 512
#define NH 8
#define HD 64
#define CSTRIDE (NB * NSEQ * DMODEL)  // 4194304

static __device__ __forceinline__ unsigned short f2bf(float f) {
    unsigned u = __builtin_bit_cast(unsigned, f);
    u += 0x7fffu + ((u >> 16) & 1u);
    return (unsigned short)(u >> 16);
}

static __device__ __forceinline__ short8 cvt8(float4 a, float4 b) {
    short8 r;
    r[0] = (short)f2bf(a.x); r[1] = (short)f2bf(a.y);
    r[2] = (short)f2bf(a.z); r[3] = (short)f2bf(a.w);
    r[4] = (short)f2bf(b.x); r[5] = (short)f2bf(b.y);
    r[6] = (short)f2bf(b.z); r[7] = (short)f2bf(b.w);
    return r;
}

static __device__ __forceinline__ unsigned cvt_pk_bf16(float lo, float hi) {
    unsigned r;
    asm("v_cvt_pk_bf16_f32 %0, %1, %2" : "=v"(r) : "v"(lo), "v"(hi));
    return r;
}

// ---------------------------------------------------------------------------
// Prepass 1: Q,K fp32 [b,n,h*64+d] -> bf16 [b,h,n,d]
// ---------------------------------------------------------------------------
__global__ __launch_bounds__(256)
void qk_convert(const float* __restrict__ x, unsigned short* __restrict__ Qbf,
                unsigned short* __restrict__ Kbf) {
    int cid = blockIdx.x * 256 + threadIdx.x;  // 2*2*4096*64 chunks of 8
    int d8 = cid & 63;
    int n = (cid >> 6) & 4095;
    int b = (cid >> 18) & 1;
    int c = cid >> 19;
    const float* src = x + (size_t)c * CSTRIDE + ((size_t)(b * 4096 + n)) * 512 + d8 * 8;
    float4 a0 = *reinterpret_cast<const float4*>(src);
    float4 a1 = *reinterpret_cast<const float4*>(src + 4);
    unsigned short* dst = (c ? Kbf : Qbf) +
        (((size_t)(b * 8 + (d8 >> 3)) * 4096 + n) * 64 + (d8 & 7) * 8);
    *reinterpret_cast<short8*>(dst) = cvt8(a0, a1);
}

// ---------------------------------------------------------------------------
// Prepass 2: V fp32 [b,n,h*64+d] -> bf16 transposed Vt[b,h,d,n]
// grid (N/64, B*H), 64x64 tiles via LDS
// ---------------------------------------------------------------------------
__global__ __launch_bounds__(256)
void v_transpose(const float* __restrict__ x, unsigned short* __restrict__ Vt) {
    __shared__ __attribute__((aligned(16))) unsigned short T[64 * 66];
    unsigned* T32 = reinterpret_cast<unsigned*>(T);

    const int tid = threadIdx.x;
    const int bh = blockIdx.y;
    const int b = bh >> 3, h = bh & 7;
    const int n0 = blockIdx.x * 64;

#pragma unroll
    for (int j = 0; j < 2; ++j) {
        int cid = tid + 256 * j;
        int ni = cid >> 3;
        int d0 = (cid & 7) * 8;
        const float* src = x + (size_t)2 * CSTRIDE +
            ((size_t)(b * 4096 + n0 + ni)) * 512 + h * 64 + d0;
        float4 a0 = *reinterpret_cast<const float4*>(src);
        float4 a1 = *reinterpret_cast<const float4*>(src + 4);
        short8 v = cvt8(a0, a1);
#pragma unroll
        for (int k = 0; k < 4; ++k) {
            unsigned pk = (unsigned)(unsigned short)v[2 * k] |
                          ((unsigned)(unsigned short)v[2 * k + 1] << 16);
            T32[ni * 33 + (d0 >> 1) + k] = pk;
        }
    }
    __syncthreads();

#pragma unroll
    for (int j = 0; j < 2; ++j) {
        int cid = tid + 256 * j;
        int di = cid >> 3;
        int k0 = (cid & 7) * 8;
        short8 o;
#pragma unroll
        for (int k = 0; k < 8; ++k) o[k] = (short)T[(k0 + k) * 66 + di];
        unsigned short* dst = Vt + ((size_t)(bh * 64 + di)) * 4096 + n0 + k0;
        *reinterpret_cast<short8*>(dst) = o;
    }
}

// ---------------------------------------------------------------------------
// Prepass 3: W fp32 [512,512] -> bf16 same layout
// ---------------------------------------------------------------------------
__global__ __launch_bounds__(256)
void w_convert(const float* __restrict__ W, unsigned short* __restrict__ Wbf) {
    int cid = blockIdx.x * 256 + threadIdx.x;  // 512*64 chunks
    int d8 = cid & 63;
    int row = cid >> 6;
    const float* src = W + (size_t)row * 512 + d8 * 8;
    float4 a0 = *reinterpret_cast<const float4*>(src);
    float4 a1 = *reinterpret_cast<const float4*>(src + 4);
    *reinterpret_cast<short8*>(Wbf + (size_t)row * 512 + d8 * 8) = cvt8(a0, a1);
}

// ---------------------------------------------------------------------------
// Flash attention (bf16 inputs): grid (64 q-tiles, 16 b*h), 4 waves.
// Swapped QK^T (mfma(K,Q) -> S^T): softmax is in-lane + 2 shfl_xor.
// ---------------------------------------------------------------------------
__global__ __launch_bounds__(256, 4)
void attn_kernel(const unsigned short* __restrict__ Qbf,
                 const unsigned short* __restrict__ Kbf,
                 const unsigned short* __restrict__ Vt,
                 unsigned short* __restrict__ Obf) {
    __shared__ __attribute__((aligned(16))) unsigned short K_lds[64 * 64];  // [key][d] swz
    __shared__ __attribute__((aligned(16))) unsigned short V_lds[64 * 64];  // [d][key] swz
    __shared__ __attribute__((aligned(16))) unsigned short P_lds[4 * 16 * 64];  // per-wave [q][key] swz

    const int tid = threadIdx.x;
    const int lane = tid & 63;
    const int wv = tid >> 6;
    const int g = lane >> 4;
    const int l4 = lane & 15;

    const int bh = blockIdx.y;
    const int b = bh >> 3, h = bh & 7;
    const int qbase = blockIdx.x * 64;

    const unsigned short* Qh = Qbf + (size_t)bh * NSEQ * HD;
    const unsigned short* Kh = Kbf + (size_t)bh * NSEQ * HD;
    const unsigned short* Vh = Vt + (size_t)bh * HD * NSEQ;

    // Q fragments: B-operand, lane holds Q[q=l4][k=c*32+g*8+j]
    short8 qf[2];
    {
        const int qrow = qbase + wv * 16 + l4;
#pragma unroll
        for (int c = 0; c < 2; ++c)
            qf[c] = *reinterpret_cast<const short8*>(Qh + (size_t)qrow * HD + c * 32 + g * 8);
    }

    f32x4 oacc[4];
#pragma unroll
    for (int dt = 0; dt < 4; ++dt) oacc[dt] = (f32x4){0.f, 0.f, 0.f, 0.f};
    float m_run = -1e30f, l_run = 0.f;

    const float ls = 0.125f * 1.44269504088896340736f;  // scale * log2(e)

    for (int kt = 0; kt < NSEQ / 64; ++kt) {
        // ---- stage K [key][d] and V [d][key], both bf16, swizzled b128 writes ----
#pragma unroll
        for (int j = 0; j < 2; ++j) {
            const int cid = tid + 256 * j;  // 512 chunks = 64 rows x 8x16B
            const int row = cid >> 3;
            const int e0 = (cid & 7) * 8;
            short8 kv = *reinterpret_cast<const short8*>(Kh + (size_t)(kt * 64 + row) * HD + e0);
            int koff = (row * 128 + e0 * 2) ^ ((row & 7) << 4);
            *reinterpret_cast<short8*>((char*)K_lds + koff) = kv;
            short8 vv = *reinterpret_cast<const short8*>(Vh + (size_t)row * NSEQ + kt * 64 + e0);
            int voff = (row * 128 + e0 * 2) ^ ((row & 7) << 4);
            *reinterpret_cast<short8*>((char*)V_lds + voff) = vv;
        }
        __syncthreads();

        // ---- S^T = K Q^T : lane holds S[key=t*16+g*4+r][q=l4], log2-scaled ----
        f32x4 p[4];
#pragma unroll
        for (int t = 0; t < 4; ++t) {
            f32x4 acc = (f32x4){0.f, 0.f, 0.f, 0.f};
#pragma unroll
            for (int c = 0; c < 2; ++c) {
                int off = ((t * 16 + l4) * 128 + (c * 32 + g * 8) * 2) ^ ((l4 & 7) << 4);
                short8 kb = *reinterpret_cast<const short8*>((const char*)K_lds + off);
                acc = MFMA16(kb, qf[c], acc);
            }
#pragma unroll
            for (int r = 0; r < 4; ++r) p[t][r] = acc[r] * ls;
        }

        // ---- online softmax: in-lane over 16 keys, then reduce across g-groups ----
        float mt0 = fmaxf(fmaxf(p[0][0], p[0][1]), fmaxf(p[0][2], p[0][3]));
        float mt1 = fmaxf(fmaxf(p[1][0], p[1][1]), fmaxf(p[1][2], p[1][3]));
        float mt2 = fmaxf(fmaxf(p[2][0], p[2][1]), fmaxf(p[2][2], p[2][3]));
        float mt3 = fmaxf(fmaxf(p[3][0], p[3][1]), fmaxf(p[3][2], p[3][3]));
        float mx = fmaxf(fmaxf(mt0, mt1), fmaxf(mt2, mt3));
        mx = fmaxf(mx, __shfl_xor(mx, 16));
        mx = fmaxf(mx, __shfl_xor(mx, 32));
        float m_new = fmaxf(m_run, mx);
        float rs = exp2f(m_run - m_new);
        m_run = m_new;

        float s = 0.f;
#pragma unroll
        for (int t = 0; t < 4; ++t)
#pragma unroll
            for (int r = 0; r < 4; ++r) {
                p[t][r] = exp2f(p[t][r] - m_new);
                s += p[t][r];
            }
        s += __shfl_xor(s, 16);
        s += __shfl_xor(s, 32);
        l_run = l_run * rs + s;

        // ---- P -> per-wave LDS: 4x cvt_pk + swizzled b64 writes ----
#pragma unroll
        for (int t = 0; t < 4; ++t) {
            uint2 pk;
            pk.x = cvt_pk_bf16(p[t][0], p[t][1]);
            pk.y = cvt_pk_bf16(p[t][2], p[t][3]);
            int off = (wv * 2048 + l4 * 128 + (t * 16 + g * 4) * 2) ^ ((l4 & 7) << 4);
            *reinterpret_cast<uint2*>((char*)P_lds + off) = pk;
        }

        // ---- rescale O, then PV ----
        float rsv[4];
#pragma unroll
        for (int r = 0; r < 4; ++r) rsv[r] = __shfl(rs, g * 4 + r);
#pragma unroll
        for (int dt = 0; dt < 4; ++dt)
#pragma unroll
            for (int r = 0; r < 4; ++r) oacc[dt][r] *= rsv[r];

#pragma unroll
        for (int c = 0; c < 2; ++c) {
            int poff = (wv * 2048 + l4 * 128 + (c * 32 + g * 8) * 2) ^ ((l4 & 7) << 4);
            short8 pa = *reinterpret_cast<const short8*>((const char*)P_lds + poff);
#pragma unroll
            for (int dt = 0; dt < 4; ++dt) {
                int voff = ((dt * 16 + l4) * 128 + (c * 32 + g * 8) * 2) ^ ((l4 & 7) << 4);
                short8 vb = *reinterpret_cast<const short8*>((const char*)V_lds + voff);
                oacc[dt] = MFMA16(pa, vb, oacc[dt]);
            }
        }
        __syncthreads();
    }

    // ---- epilogue: O = acc / l, write bf16 [B, N, D] ----
    float linv[4];
#pragma unroll
    for (int r = 0; r < 4; ++r) linv[r] = 1.0f / __shfl(l_run, g * 4 + r);
#pragma unroll
    for (int r = 0; r < 4; ++r) {
        int qrow = qbase + wv * 16 + g * 4 + r;
#pragma unroll
        for (int dt = 0; dt < 4; ++dt) {
            Obf[(size_t)(b * NSEQ + qrow) * DMODEL + h * HD + dt * 16 + l4] =
                f2bf(oacc[dt][r] * linv[r]);
        }
    }
}

// ---------------------------------------------------------------------------
// Projection: Y[8192,512] = O_bf16 @ Wbf^T + bias
// ---------------------------------------------------------------------------
__global__ __launch_bounds__(256, 4)
void proj_kernel(const unsigned short* __restrict__ Obf, const unsigned short* __restrict__ Wbf,
                 const float* __restrict__ bias, float* __restrict__ out) {
    __shared__ __attribute__((aligned(16))) unsigned short W_lds[64 * 64];  // [j][k] swz

    const int tid = threadIdx.x;
    const int lane = tid & 63;
    const int wv = tid >> 6;
    const int g = lane >> 4;
    const int l4 = lane & 15;

    const int bm = blockIdx.x;
    const int bn = blockIdx.y;

    f32x4 acc[4];
#pragma unroll
    for (int jt = 0; jt < 4; ++jt) acc[jt] = (f32x4){0.f, 0.f, 0.f, 0.f};

    for (int kc = 0; kc < DMODEL / 64; ++kc) {
#pragma unroll
        for (int j = 0; j < 2; ++j) {
            int cid = tid + 256 * j;
            int row = cid >> 3;
            int e0 = (cid & 7) * 8;
            short8 wv8 = *reinterpret_cast<const short8*>(
                Wbf + (size_t)(bn * 64 + row) * DMODEL + kc * 64 + e0);
            int off = (row * 128 + e0 * 2) ^ ((row & 7) << 4);
            *reinterpret_cast<short8*>((char*)W_lds + off) = wv8;
        }
        __syncthreads();

#pragma unroll
        for (int sub = 0; sub < 2; ++sub) {
            const unsigned short* ap =
                Obf + (size_t)(bm * 64 + wv * 16 + l4) * DMODEL + kc * 64 + sub * 32 + g * 8;
            short8 a = *reinterpret_cast<const short8*>(ap);
#pragma unroll
            for (int jt = 0; jt < 4; ++jt) {
                int jj = jt * 16 + l4;
                int off = (jj * 128 + (sub * 32 + g * 8) * 2) ^ ((jj & 7) << 4);
                short8 wb = *reinterpret_cast<const short8*>((const char*)W_lds + off);
                acc[jt] = MFMA16(a, wb, acc[jt]);
            }
        }
        __syncthreads();
    }

#pragma unroll
    for (int jt = 0; jt < 4; ++jt) {
        int jg = bn * 64 + jt * 16 + l4;
        float bj = bias[jg];
#pragma unroll
        for (int r = 0; r < 4; ++r) {
            int ig = bm * 64 + wv * 16 + g * 4 + r;
            out[(size_t)ig * DMODEL + jg] = acc[jt][r] + bj;
        }
    }
}

extern "C" void kernel_launch(void* const* d_in, const int* in_sizes, int n_in,
                              void* d_out, int out_size, void* d_ws, size_t ws_size,
                              hipStream_t stream) {
    const float* x = (const float*)d_in[0];     // [3, 2, 4096, 512] fp32
    const float* W = (const float*)d_in[1];     // [512, 512] fp32
    const float* bias = (const float*)d_in[2];  // [512] fp32
    float* out = (float*)d_out;                 // [2, 4096, 512] fp32

    char* ws = (char*)d_ws;
    unsigned short* Obf = (unsigned short*)(ws);                // 8 MB
    unsigned short* Qbf = (unsigned short*)(ws + (8u << 20));   // 8 MB
    unsigned short* Kbf = (unsigned short*)(ws + (16u << 20));  // 8 MB
    unsigned short* Vt = (unsigned short*)(ws + (24u << 20));   // 8 MB
    unsigned short* Wbf = (unsigned short*)(ws + (32u << 20));  // 0.5 MB

    qk_convert<<<4096, 256, 0, stream>>>(x, Qbf, Kbf);
    v_transpose<<<dim3(NSEQ / 64, NB * NH), 256, 0, stream>>>(x, Vt);
    w_convert<<<128, 256, 0, stream>>>(W, Wbf);

    dim3 gA(NSEQ / 64, NB * NH);  // (64, 16)
    attn_kernel<<<gA, 256, 0, stream>>>(Qbf, Kbf, Vt, Obf);

    dim3 gP(NB * NSEQ / 64, DMODEL / 64);  // (128, 8)
    proj_kernel<<<gP, 256, 0, stream>>>(Obf, Wbf, bias, out);
}

// Round 3
// 138.721 us; speedup vs baseline: 2.6584x; 1.3456x over previous
//
#include <hip/hip_runtime.h>
#include <hip/hip_bf16.h>

typedef __attribute__((ext_vector_type(8))) short short8;
typedef __attribute__((ext_vector_type(4))) float f32x4;

#define MFMA16(a, b, c) __builtin_amdgcn_mfma_f32_16x16x32_bf16((a), (b), (c), 0, 0, 0)

// dims
#define NB 2
#define NSEQ 4096
#define DMODEL 512
#define NH 8
#define HD 64
#define CSTRIDE (NB * NSEQ * DMODEL)  // 4194304

#define QSCALE 0.18033688011112042f  // 0.125 * log2(e), folded into Q prepass

static __device__ __forceinline__ unsigned short f2bf(float f) {
    unsigned u = __builtin_bit_cast(unsigned, f);
    u += 0x7fffu + ((u >> 16) & 1u);
    return (unsigned short)(u >> 16);
}

static __device__ __forceinline__ short8 cvt8(float4 a, float4 b) {
    short8 r;
    r[0] = (short)f2bf(a.x); r[1] = (short)f2bf(a.y);
    r[2] = (short)f2bf(a.z); r[3] = (short)f2bf(a.w);
    r[4] = (short)f2bf(b.x); r[5] = (short)f2bf(b.y);
    r[6] = (short)f2bf(b.z); r[7] = (short)f2bf(b.w);
    return r;
}

static __device__ __forceinline__ unsigned cvt_pk_bf16(float lo, float hi) {
    unsigned r;
    asm("v_cvt_pk_bf16_f32 %0, %1, %2" : "=v"(r) : "v"(lo), "v"(hi));
    return r;
}

static __device__ __forceinline__ float max3f(float a, float b, float c) {
    return fmaxf(fmaxf(a, b), c);  // fuses to v_max3_f32
}

// ---------------------------------------------------------------------------
// Prepass 1: Q,K fp32 [b,n,h*64+d] -> bf16 [b,h,n,d]; Q pre-scaled by QSCALE.
// ---------------------------------------------------------------------------
__global__ __launch_bounds__(256)
void qk_convert(const float* __restrict__ x, unsigned short* __restrict__ Qbf,
                unsigned short* __restrict__ Kbf) {
    int cid = blockIdx.x * 256 + threadIdx.x;  // 2*2*4096*64 chunks of 8
    int d8 = cid & 63;
    int n = (cid >> 6) & 4095;
    int b = (cid >> 18) & 1;
    int c = cid >> 19;
    const float* src = x + (size_t)c * CSTRIDE + ((size_t)(b * 4096 + n)) * 512 + d8 * 8;
    float4 a0 = *reinterpret_cast<const float4*>(src);
    float4 a1 = *reinterpret_cast<const float4*>(src + 4);
    float sc = c ? 1.0f : QSCALE;
    a0.x *= sc; a0.y *= sc; a0.z *= sc; a0.w *= sc;
    a1.x *= sc; a1.y *= sc; a1.z *= sc; a1.w *= sc;
    unsigned short* dst = (c ? Kbf : Qbf) +
        (((size_t)(b * 8 + (d8 >> 3)) * 4096 + n) * 64 + (d8 & 7) * 8);
    *reinterpret_cast<short8*>(dst) = cvt8(a0, a1);
}

// ---------------------------------------------------------------------------
// Prepass 2: V fp32 [b,n,h*64+d] -> bf16 transposed Vt[b,h,d,n]
// ---------------------------------------------------------------------------
__global__ __launch_bounds__(256)
void v_transpose(const float* __restrict__ x, unsigned short* __restrict__ Vt) {
    __shared__ __attribute__((aligned(16))) unsigned short T[64 * 66];
    unsigned* T32 = reinterpret_cast<unsigned*>(T);

    const int tid = threadIdx.x;
    const int bh = blockIdx.y;
    const int b = bh >> 3, h = bh & 7;
    const int n0 = blockIdx.x * 64;

#pragma unroll
    for (int j = 0; j < 2; ++j) {
        int cid = tid + 256 * j;
        int ni = cid >> 3;
        int d0 = (cid & 7) * 8;
        const float* src = x + (size_t)2 * CSTRIDE +
            ((size_t)(b * 4096 + n0 + ni)) * 512 + h * 64 + d0;
        float4 a0 = *reinterpret_cast<const float4*>(src);
        float4 a1 = *reinterpret_cast<const float4*>(src + 4);
        short8 v = cvt8(a0, a1);
#pragma unroll
        for (int k = 0; k < 4; ++k) {
            unsigned pk = (unsigned)(unsigned short)v[2 * k] |
                          ((unsigned)(unsigned short)v[2 * k + 1] << 16);
            T32[ni * 33 + (d0 >> 1) + k] = pk;
        }
    }
    __syncthreads();

#pragma unroll
    for (int j = 0; j < 2; ++j) {
        int cid = tid + 256 * j;
        int di = cid >> 3;
        int k0 = (cid & 7) * 8;
        short8 o;
#pragma unroll
        for (int k = 0; k < 8; ++k) o[k] = (short)T[(k0 + k) * 66 + di];
        unsigned short* dst = Vt + ((size_t)(bh * 64 + di)) * 4096 + n0 + k0;
        *reinterpret_cast<short8*>(dst) = o;
    }
}

// ---------------------------------------------------------------------------
// Prepass 3: W fp32 [512,512] -> bf16
// ---------------------------------------------------------------------------
__global__ __launch_bounds__(256)
void w_convert(const float* __restrict__ W, unsigned short* __restrict__ Wbf) {
    int cid = blockIdx.x * 256 + threadIdx.x;
    int d8 = cid & 63;
    int row = cid >> 6;
    const float* src = W + (size_t)row * 512 + d8 * 8;
    float4 a0 = *reinterpret_cast<const float4*>(src);
    float4 a1 = *reinterpret_cast<const float4*>(src + 4);
    *reinterpret_cast<short8*>(Wbf + (size_t)row * 512 + d8 * 8) = cvt8(a0, a1);
}

// ---------------------------------------------------------------------------
// Flash attention: grid (32 q-tiles of 128, 16 b*h), 4 waves x 32 q-rows.
// Swapped QK^T; K/V fragments reused across 2 q-subtiles; 2-phase prefetch;
// defer-max online softmax with raw v_exp_f32.
// ---------------------------------------------------------------------------
__global__ __launch_bounds__(256, 2)
void attn_kernel(const unsigned short* __restrict__ Qbf,
                 const unsigned short* __restrict__ Kbf,
                 const unsigned short* __restrict__ Vt,
                 unsigned short* __restrict__ Obf) {
    __shared__ __attribute__((aligned(16))) unsigned short K_lds[64 * 64];      // [key][d] swz
    __shared__ __attribute__((aligned(16))) unsigned short V_lds[64 * 64];      // [d][key] swz
    __shared__ __attribute__((aligned(16))) unsigned short P_lds[4 * 32 * 64];  // per-wave [q][key] swz

    const int tid = threadIdx.x;
    const int lane = tid & 63;
    const int wv = tid >> 6;
    const int g = lane >> 4;
    const int l4 = lane & 15;

    const int bh = blockIdx.y;
    const int b = bh >> 3, h = bh & 7;
    const int qbase = blockIdx.x * 128 + wv * 32;

    const unsigned short* Qh = Qbf + (size_t)bh * NSEQ * HD;
    const unsigned short* Kh = Kbf + (size_t)bh * NSEQ * HD;
    const unsigned short* Vh = Vt + (size_t)bh * HD * NSEQ;

    // Q fragments: B-operand, lane holds Q[q = u*16 + l4][k = c*32 + g*8 + j]
    short8 qf[2][2];
#pragma unroll
    for (int u = 0; u < 2; ++u)
#pragma unroll
        for (int c = 0; c < 2; ++c)
            qf[u][c] = *reinterpret_cast<const short8*>(
                Qh + (size_t)(qbase + u * 16 + l4) * HD + c * 32 + g * 8);

    f32x4 oacc[2][4];
#pragma unroll
    for (int u = 0; u < 2; ++u)
#pragma unroll
        for (int dt = 0; dt < 4; ++dt) oacc[u][dt] = (f32x4){0.f, 0.f, 0.f, 0.f};
    float m_run[2] = {-1e30f, -1e30f}, l_run[2] = {0.f, 0.f};

    // staging geometry: 512 chunks of 8 bf16 per 64x64 tile, 2 per thread
    const int row0 = tid >> 3;             // j=0 row
    const int row1 = (tid + 256) >> 3;     // j=1 row
    const int e0 = (tid & 7) * 8;

    // preload tile 0
    short8 kreg[2], vreg[2];
    kreg[0] = *reinterpret_cast<const short8*>(Kh + (size_t)row0 * HD + e0);
    kreg[1] = *reinterpret_cast<const short8*>(Kh + (size_t)row1 * HD + e0);
    vreg[0] = *reinterpret_cast<const short8*>(Vh + (size_t)row0 * NSEQ + e0);
    vreg[1] = *reinterpret_cast<const short8*>(Vh + (size_t)row1 * NSEQ + e0);

    for (int kt = 0; kt < NSEQ / 64; ++kt) {
        __syncthreads();  // everyone done reading prev tile
        {
            int o0 = (row0 * 128 + e0 * 2) ^ ((row0 & 7) << 4);
            int o1 = (row1 * 128 + e0 * 2) ^ ((row1 & 7) << 4);
            *reinterpret_cast<short8*>((char*)K_lds + o0) = kreg[0];
            *reinterpret_cast<short8*>((char*)K_lds + o1) = kreg[1];
            *reinterpret_cast<short8*>((char*)V_lds + o0) = vreg[0];
            *reinterpret_cast<short8*>((char*)V_lds + o1) = vreg[1];
        }
        {   // prefetch next tile (wraps harmlessly on last iter)
            int nt = (kt + 1) & (NSEQ / 64 - 1);
            kreg[0] = *reinterpret_cast<const short8*>(Kh + (size_t)(nt * 64 + row0) * HD + e0);
            kreg[1] = *reinterpret_cast<const short8*>(Kh + (size_t)(nt * 64 + row1) * HD + e0);
            vreg[0] = *reinterpret_cast<const short8*>(Vh + (size_t)row0 * NSEQ + nt * 64 + e0);
            vreg[1] = *reinterpret_cast<const short8*>(Vh + (size_t)row1 * NSEQ + nt * 64 + e0);
        }
        __syncthreads();  // LDS tile ready

        // ---- S^T = K Q^T : lane holds S[key=t*16+g*4+r][q=l4] (log2-scaled) ----
        f32x4 st[2][4];
#pragma unroll
        for (int t = 0; t < 4; ++t) {
            int base = (t * 16 + l4) * 128;
            int sw = (l4 & 7) << 4;
            short8 kb0 = *reinterpret_cast<const short8*>(
                (const char*)K_lds + ((base + (g * 8) * 2) ^ sw));
            short8 kb1 = *reinterpret_cast<const short8*>(
                (const char*)K_lds + ((base + (32 + g * 8) * 2) ^ sw));
#pragma unroll
            for (int u = 0; u < 2; ++u) {
                f32x4 a = (f32x4){0.f, 0.f, 0.f, 0.f};
                a = MFMA16(kb0, qf[u][0], a);
                a = MFMA16(kb1, qf[u][1], a);
                st[u][t] = a;
            }
        }

        // ---- online softmax per q-subtile (defer-max, raw v_exp) ----
#pragma unroll
        for (int u = 0; u < 2; ++u) {
            float mx = max3f(st[u][0][0], st[u][0][1], st[u][0][2]);
            mx = max3f(mx, st[u][0][3], st[u][1][0]);
            mx = max3f(mx, st[u][1][1], st[u][1][2]);
            mx = max3f(mx, st[u][1][3], st[u][2][0]);
            mx = max3f(mx, st[u][2][1], st[u][2][2]);
            mx = max3f(mx, st[u][2][3], st[u][3][0]);
            mx = max3f(mx, st[u][3][1], st[u][3][2]);
            mx = fmaxf(mx, st[u][3][3]);
            mx = fmaxf(mx, __shfl_xor(mx, 16));
            mx = fmaxf(mx, __shfl_xor(mx, 32));

            bool resc = __any(mx > m_run[u] + 8.0f);
            float rs = 1.0f;
            if (resc) {
                float mn = fmaxf(m_run[u], mx);
                rs = __builtin_amdgcn_exp2f(m_run[u] - mn);
                m_run[u] = mn;
            }
            float s = 0.f;
#pragma unroll
            for (int t = 0; t < 4; ++t)
#pragma unroll
                for (int r = 0; r < 4; ++r) {
                    float p = __builtin_amdgcn_exp2f(st[u][t][r] - m_run[u]);
                    st[u][t][r] = p;
                    s += p;
                }
            s += __shfl_xor(s, 16);
            s += __shfl_xor(s, 32);
            if (resc) {
                l_run[u] = l_run[u] * rs + s;
                float rsv[4];
#pragma unroll
                for (int r = 0; r < 4; ++r) rsv[r] = __shfl(rs, g * 4 + r);
#pragma unroll
                for (int dt = 0; dt < 4; ++dt)
#pragma unroll
                    for (int r = 0; r < 4; ++r) oacc[u][dt][r] *= rsv[r];
            } else {
                l_run[u] += s;
            }

            // P -> per-wave LDS (bf16): 4x (2 cvt_pk + b64 swz write)
#pragma unroll
            for (int t = 0; t < 4; ++t) {
                uint2 pk;
                pk.x = cvt_pk_bf16(st[u][t][0], st[u][t][1]);
                pk.y = cvt_pk_bf16(st[u][t][2], st[u][t][3]);
                int off = (wv * 4096 + (u * 16 + l4) * 128 + (t * 16 + g * 4) * 2) ^
                          ((l4 & 7) << 4);
                *reinterpret_cast<uint2*>((char*)P_lds + off) = pk;
            }
        }

        // ---- PV: V fragments reused across both q-subtiles ----
#pragma unroll
        for (int c = 0; c < 2; ++c) {
            int sw = (l4 & 7) << 4;
            int cb = (c * 32 + g * 8) * 2;
            short8 pa0 = *reinterpret_cast<const short8*>(
                (const char*)P_lds + ((wv * 4096 + l4 * 128 + cb) ^ sw));
            short8 pa1 = *reinterpret_cast<const short8*>(
                (const char*)P_lds + ((wv * 4096 + (16 + l4) * 128 + cb) ^ sw));
#pragma unroll
            for (int dt = 0; dt < 4; ++dt) {
                short8 vb = *reinterpret_cast<const short8*>(
                    (const char*)V_lds + (((dt * 16 + l4) * 128 + cb) ^ sw));
                oacc[0][dt] = MFMA16(pa0, vb, oacc[0][dt]);
                oacc[1][dt] = MFMA16(pa1, vb, oacc[1][dt]);
            }
        }
    }

    // ---- epilogue ----
#pragma unroll
    for (int u = 0; u < 2; ++u) {
        float linv[4];
#pragma unroll
        for (int r = 0; r < 4; ++r) linv[r] = 1.0f / __shfl(l_run[u], g * 4 + r);
#pragma unroll
        for (int r = 0; r < 4; ++r) {
            int qrow = qbase + u * 16 + g * 4 + r;
#pragma unroll
            for (int dt = 0; dt < 4; ++dt) {
                Obf[(size_t)(b * NSEQ + qrow) * DMODEL + h * HD + dt * 16 + l4] =
                    f2bf(oacc[u][dt][r] * linv[r]);
            }
        }
    }
}

// ---------------------------------------------------------------------------
// Projection: Y[8192,512] = O_bf16 @ Wbf^T + bias
// ---------------------------------------------------------------------------
__global__ __launch_bounds__(256, 4)
void proj_kernel(const unsigned short* __restrict__ Obf, const unsigned short* __restrict__ Wbf,
                 const float* __restrict__ bias, float* __restrict__ out) {
    __shared__ __attribute__((aligned(16))) unsigned short W_lds[64 * 64];  // [j][k] swz

    const int tid = threadIdx.x;
    const int lane = tid & 63;
    const int wv = tid >> 6;
    const int g = lane >> 4;
    const int l4 = lane & 15;

    const int bm = blockIdx.x;
    const int bn = blockIdx.y;

    f32x4 acc[4];
#pragma unroll
    for (int jt = 0; jt < 4; ++jt) acc[jt] = (f32x4){0.f, 0.f, 0.f, 0.f};

    for (int kc = 0; kc < DMODEL / 64; ++kc) {
#pragma unroll
        for (int j = 0; j < 2; ++j) {
            int cid = tid + 256 * j;
            int row = cid >> 3;
            int ee = (cid & 7) * 8;
            short8 wv8 = *reinterpret_cast<const short8*>(
                Wbf + (size_t)(bn * 64 + row) * DMODEL + kc * 64 + ee);
            int off = (row * 128 + ee * 2) ^ ((row & 7) << 4);
            *reinterpret_cast<short8*>((char*)W_lds + off) = wv8;
        }
        __syncthreads();

#pragma unroll
        for (int sub = 0; sub < 2; ++sub) {
            const unsigned short* ap =
                Obf + (size_t)(bm * 64 + wv * 16 + l4) * DMODEL + kc * 64 + sub * 32 + g * 8;
            short8 a = *reinterpret_cast<const short8*>(ap);
#pragma unroll
            for (int jt = 0; jt < 4; ++jt) {
                int jj = jt * 16 + l4;
                int off = (jj * 128 + (sub * 32 + g * 8) * 2) ^ ((jj & 7) << 4);
                short8 wb = *reinterpret_cast<const short8*>((const char*)W_lds + off);
                acc[jt] = MFMA16(a, wb, acc[jt]);
            }
        }
        __syncthreads();
    }

#pragma unroll
    for (int jt = 0; jt < 4; ++jt) {
        int jg = bn * 64 + jt * 16 + l4;
        float bj = bias[jg];
#pragma unroll
        for (int r = 0; r < 4; ++r) {
            int ig = bm * 64 + wv * 16 + g * 4 + r;
            out[(size_t)ig * DMODEL + jg] = acc[jt][r] + bj;
        }
    }
}

extern "C" void kernel_launch(void* const* d_in, const int* in_sizes, int n_in,
                              void* d_out, int out_size, void* d_ws, size_t ws_size,
                              hipStream_t stream) {
    const float* x = (const float*)d_in[0];     // [3, 2, 4096, 512] fp32
    const float* W = (const float*)d_in[1];     // [512, 512] fp32
    const float* bias = (const float*)d_in[2];  // [512] fp32
    float* out = (float*)d_out;                 // [2, 4096, 512] fp32

    char* ws = (char*)d_ws;
    unsigned short* Obf = (unsigned short*)(ws);                // 8 MB
    unsigned short* Qbf = (unsigned short*)(ws + (8u << 20));   // 8 MB
    unsigned short* Kbf = (unsigned short*)(ws + (16u << 20));  // 8 MB
    unsigned short* Vt = (unsigned short*)(ws + (24u << 20));   // 8 MB
    unsigned short* Wbf = (unsigned short*)(ws + (32u << 20));  // 0.5 MB

    qk_convert<<<4096, 256, 0, stream>>>(x, Qbf, Kbf);
    v_transpose<<<dim3(NSEQ / 64, NB * NH), 256, 0, stream>>>(x, Vt);
    w_convert<<<128, 256, 0, stream>>>(W, Wbf);

    dim3 gA(NSEQ / 128, NB * NH);  // (32, 16) = 512 blocks
    attn_kernel<<<gA, 256, 0, stream>>>(Qbf, Kbf, Vt, Obf);

    dim3 gP(NB * NSEQ / 64, DMODEL / 64);  // (128, 8)
    proj_kernel<<<gP, 256, 0, stream>>>(Obf, Wbf, bias, out);
}